// Round 14
// baseline (804.818 us; speedup 1.0000x reference)
//
#include <hip/hip_runtime.h>
#include <math.h>

#define BB 1024
#define TT 512

typedef __attribute__((ext_vector_type(8))) short  short8;
typedef __attribute__((ext_vector_type(4))) float  floatx4;

__device__ __forceinline__ float fast_rcp(float x){ return __builtin_amdgcn_rcpf(x); }
__device__ __forceinline__ float sigmoidf_(float x){ return fast_rcp(1.0f + __expf(-x)); }
__device__ __forceinline__ float tanhf_(float x){
    float t = __expf(2.0f * x);
    return 1.0f - 2.0f * fast_rcp(t + 1.0f);
}
__device__ __forceinline__ unsigned short f2bf(float f){
    unsigned u = __builtin_bit_cast(unsigned, f);
    u += 0x7fffu + ((u >> 16) & 1u);
    return (unsigned short)(u >> 16);
}
__device__ __forceinline__ float bf2f(unsigned short u){
    return __builtin_bit_cast(float, ((unsigned)u) << 16);
}

// Barrier WITHOUT the vmcnt(0) drain. __syncthreads compiles to
// `s_waitcnt vmcnt(0) lgkmcnt(0); s_barrier` — in a loop with a global store
// per step that forces a ~500-900 cyc HBM store-ack drain every iteration
// (R13: 1520 cyc/step vs ~400 chain). The LDS h-exchange only needs DS-op
// visibility: lgkmcnt(0) + s_barrier. Global stores retire async; prefetch
// loads wait at their true use via compiler-inserted vmcnt(N).
__device__ __forceinline__ void lds_barrier(){
    asm volatile("s_waitcnt lgkmcnt(0)\n\ts_barrier" ::: "memory");
}

// ---------------------------------------------------------------------------
// MFMA-batched biGRU recurrence, i-half-split across 2 waves.
// Block = 128 thr = 2 waves = one 16-sequence tile (one (batch16, dir) pair).
// Wave wid owns gate-tiles {r,z,n} for i in [wid*16, wid*16+16): complete
// gate triples IN-LANE (D: col=lane&15 gate, row=quad*4+reg batch). h: f32
// master in regs; bf16 copy in a double-buffered LDS tile; one lds_barrier
// per step. h1 store: the A-fragment read at step t IS h_{t-1} in store
// layout -> wave0 stores it; no extra ds_read.
// ---------------------------------------------------------------------------
__global__ __launch_bounds__(128, 1) void gru_l0(
    const float* __restrict__ x,      // (B,T,4) f32
    const float* __restrict__ w_ih,   // (2,96,4)
    const float* __restrict__ w_hh,   // (2,96,32)
    const float* __restrict__ b_ih,   // (2,96)
    const float* __restrict__ b_hh,   // (2,96)
    unsigned short* __restrict__ h1)  // (B,T,64) bf16
{
    const int tile = blockIdx.x;      // 0..127
    const int bt   = tile >> 1;
    const int d    = tile & 1;
    const int b0   = bt * 16;
    const int tid  = threadIdx.x;
    const int wid  = tid >> 6;        // i-half this wave owns
    const int L    = tid & 63;
    const int col  = L & 15;
    const int quad = L >> 4;

    // B-fragments: B[n=col][k=quad*8+j]
    short8 bhh[3], bih[3];
    #pragma unroll
    for (int g = 0; g < 3; ++g){
        const int row = d*96 + g*32 + wid*16 + col;
        short8 f;
        #pragma unroll
        for (int j = 0; j < 8; ++j) f[j] = f2bf(w_hh[(size_t)row*32 + quad*8 + j]);
        bhh[g] = f;
        short8 fi = {0,0,0,0,0,0,0,0};
        if (quad == 0){
            #pragma unroll
            for (int j = 0; j < 4; ++j) fi[j] = f2bf(w_ih[(size_t)row*4 + j]);
        }
        bih[g] = fi;
    }
    const int gr = d*96 + wid*16 + col;
    const float br  = b_ih[gr]      + b_hh[gr];
    const float bz  = b_ih[gr + 32] + b_hh[gr + 32];
    const float bni = b_ih[gr + 64];
    const float bhn = b_hh[gr + 64];

    __shared__ unsigned short hsh[2][16*40];
    for (int k = tid; k < 16*40; k += 128) hsh[0][k] = 0;
    float hr[4] = {0.f, 0.f, 0.f, 0.f};
    __syncthreads();

    const size_t xrow = (size_t)(b0 + col) * TT;
    float4 xc = {0,0,0,0}, xn1 = {0,0,0,0};
    if (quad == 0){
        xc  = *(const float4*)(x + (xrow + (d ? TT-1 : 0))*4);
        xn1 = *(const float4*)(x + (xrow + (d ? TT-2 : 1))*4);
    }

    const floatx4 z4 = {0.f,0.f,0.f,0.f};
    for (int t = 0; t < TT; ++t){
        const int rb = t & 1, wb = rb ^ 1;
        const short8 ah = *(const short8*)(&hsh[rb][col*40 + quad*8]);  // = h_{t-1}
        short8 ax = {0,0,0,0,0,0,0,0};
        if (quad == 0){ ax[0]=f2bf(xc.x); ax[1]=f2bf(xc.y); ax[2]=f2bf(xc.z); ax[3]=f2bf(xc.w); }

        floatx4 xg[3], hg[3];
        #pragma unroll
        for (int g = 0; g < 3; ++g)
            xg[g] = __builtin_amdgcn_mfma_f32_16x16x32_bf16(ax, bih[g], z4, 0, 0, 0);
        #pragma unroll
        for (int g = 0; g < 3; ++g)
            hg[g] = __builtin_amdgcn_mfma_f32_16x16x32_bf16(ah, bhh[g], z4, 0, 0, 0);

        // store h_{t-1} (== ah, already in store layout) — wave0 only
        if (wid == 0 && t > 0){
            const int txp = d ? (TT - t) : (t - 1);
            *(short8*)(&h1[((size_t)(b0 + col)*TT + txp)*64 + d*32 + quad*8]) = ah;
        }
        // prefetch x for t+2
        float4 xn2 = xn1;
        if (quad == 0 && t + 2 < TT)
            xn2 = *(const float4*)(x + (xrow + (d ? TT-3-t : t+2))*4);

        #pragma unroll
        for (int r4 = 0; r4 < 4; ++r4){
            const float rg = sigmoidf_(xg[0][r4] + hg[0][r4] + br);
            const float zg = sigmoidf_(xg[1][r4] + hg[1][r4] + bz);
            const float ng = tanhf_(xg[2][r4] + bni + rg*(hg[2][r4] + bhn));
            hr[r4] = ng + zg*(hr[r4] - ng);
            hsh[wb][(quad*4 + r4)*40 + wid*16 + col] = f2bf(hr[r4]);
        }
        lds_barrier();
        xc = xn1; xn1 = xn2;
    }
    // epilogue: h_{TT-1} sits in hsh[TT & 1]
    if (wid == 0){
        const short8 ah = *(const short8*)(&hsh[TT & 1][col*40 + quad*8]);
        const int txl = d ? 0 : TT-1;
        *(short8*)(&h1[((size_t)(b0 + col)*TT + txl)*64 + d*32 + quad*8]) = ah;
    }
}

// ---------------------------------------------------------------------------
// Layer 1: same structure; projection fused as 6 xg MFMAs (K=64 in 2 chunks)
// reading bf16 h1 rows (2-step register prefetch covers HBM latency).
// ---------------------------------------------------------------------------
__global__ __launch_bounds__(128, 1) void gru_l1(
    const unsigned short* __restrict__ h1,   // (B,T,64) bf16
    const float* __restrict__ w_ih,   // (2,96,64)
    const float* __restrict__ w_hh,   // (2,96,32)
    const float* __restrict__ b_ih,   // (2,96)
    const float* __restrict__ b_hh,   // (2,96)
    unsigned short* __restrict__ out2) // (B,T,64) bf16
{
    const int tile = blockIdx.x;
    const int bt   = tile >> 1;
    const int d    = tile & 1;
    const int b0   = bt * 16;
    const int tid  = threadIdx.x;
    const int wid  = tid >> 6;
    const int L    = tid & 63;
    const int col  = L & 15;
    const int quad = L >> 4;

    short8 bhh[3], bi0[3], bi1[3];
    #pragma unroll
    for (int g = 0; g < 3; ++g){
        const int row = d*96 + g*32 + wid*16 + col;
        short8 f, g0, g1;
        #pragma unroll
        for (int j = 0; j < 8; ++j){
            f[j]  = f2bf(w_hh[(size_t)row*32 + quad*8 + j]);
            g0[j] = f2bf(w_ih[(size_t)row*64 +      quad*8 + j]);
            g1[j] = f2bf(w_ih[(size_t)row*64 + 32 + quad*8 + j]);
        }
        bhh[g] = f; bi0[g] = g0; bi1[g] = g1;
    }
    const int gr = d*96 + wid*16 + col;
    const float br  = b_ih[gr]      + b_hh[gr];
    const float bz  = b_ih[gr + 32] + b_hh[gr + 32];
    const float bni = b_ih[gr + 64];
    const float bhn = b_hh[gr + 64];

    __shared__ unsigned short hsh[2][16*40];
    for (int k = tid; k < 16*40; k += 128) hsh[0][k] = 0;
    float hr[4] = {0.f, 0.f, 0.f, 0.f};
    __syncthreads();

    const size_t arow = (size_t)(b0 + col) * TT;
    short8 a0c, a1c, a0n, a1n;
    {
        const int tx0 = d ? TT-1 : 0;
        a0c = *(const short8*)(&h1[(arow + tx0)*64 +      quad*8]);
        a1c = *(const short8*)(&h1[(arow + tx0)*64 + 32 + quad*8]);
        const int tx1 = d ? TT-2 : 1;
        a0n = *(const short8*)(&h1[(arow + tx1)*64 +      quad*8]);
        a1n = *(const short8*)(&h1[(arow + tx1)*64 + 32 + quad*8]);
    }

    const floatx4 z4 = {0.f,0.f,0.f,0.f};
    for (int t = 0; t < TT; ++t){
        const int rb = t & 1, wb = rb ^ 1;
        const short8 ah = *(const short8*)(&hsh[rb][col*40 + quad*8]);  // h_{t-1}

        floatx4 xg[3], hg[3];
        #pragma unroll
        for (int g = 0; g < 3; ++g){
            floatx4 acc = __builtin_amdgcn_mfma_f32_16x16x32_bf16(a0c, bi0[g], z4, 0, 0, 0);
            xg[g]       = __builtin_amdgcn_mfma_f32_16x16x32_bf16(a1c, bi1[g], acc, 0, 0, 0);
        }
        #pragma unroll
        for (int g = 0; g < 3; ++g)
            hg[g] = __builtin_amdgcn_mfma_f32_16x16x32_bf16(ah, bhh[g], z4, 0, 0, 0);

        if (wid == 0 && t > 0){
            const int txp = d ? (TT - t) : (t - 1);
            *(short8*)(&out2[((size_t)(b0 + col)*TT + txp)*64 + d*32 + quad*8]) = ah;
        }
        // prefetch h1 row for t+2
        short8 a02 = a0n, a12 = a1n;
        if (t + 2 < TT){
            const int tx2 = d ? (TT-3-t) : (t+2);
            a02 = *(const short8*)(&h1[(arow + tx2)*64 +      quad*8]);
            a12 = *(const short8*)(&h1[(arow + tx2)*64 + 32 + quad*8]);
        }

        #pragma unroll
        for (int r4 = 0; r4 < 4; ++r4){
            const float rg = sigmoidf_(xg[0][r4] + hg[0][r4] + br);
            const float zg = sigmoidf_(xg[1][r4] + hg[1][r4] + bz);
            const float ng = tanhf_(xg[2][r4] + bni + rg*(hg[2][r4] + bhn));
            hr[r4] = ng + zg*(hr[r4] - ng);
            hsh[wb][(quad*4 + r4)*40 + wid*16 + col] = f2bf(hr[r4]);
        }
        lds_barrier();
        a0c = a0n; a1c = a1n; a0n = a02; a1n = a12;
    }
    if (wid == 0){
        const short8 ah = *(const short8*)(&hsh[TT & 1][col*40 + quad*8]);
        const int txl = d ? 0 : TT-1;
        *(short8*)(&out2[((size_t)(b0 + col)*TT + txl)*64 + d*32 + quad*8]) = ah;
    }
}

// Attention pooling + FC + sigmoid (bf16 out2 input). One block per b.
__global__ __launch_bounds__(256) void attn_fc(
    const unsigned short* __restrict__ out2, // (B,T,64) bf16
    const float* __restrict__ attn_w, const float* __restrict__ attn_b,
    const float* __restrict__ fc_w,   const float* __restrict__ fc_b,
    float* __restrict__ out)
{
    const int b    = blockIdx.x;
    const int tid  = threadIdx.x;
    const int wave = tid >> 6;
    const int lane = tid & 63;

    __shared__ float logit_sh[TT];
    __shared__ float red_sh[4];
    __shared__ float ctx_sh[4][64];

    const float aw = attn_w[lane];
    const float ab = attn_b[0];

    for (int t = wave; t < TT; t += 4) {
        float v = bf2f(out2[((size_t)b*TT + t)*64 + lane]) * aw;
        #pragma unroll
        for (int off = 32; off > 0; off >>= 1) v += __shfl_xor(v, off, 64);
        if (lane == 0) logit_sh[t] = v + ab;
    }
    __syncthreads();

    float m = -INFINITY;
    for (int t = tid; t < TT; t += 256) m = fmaxf(m, logit_sh[t]);
    #pragma unroll
    for (int off = 32; off > 0; off >>= 1) m = fmaxf(m, __shfl_xor(m, off, 64));
    if (lane == 0) red_sh[wave] = m;
    __syncthreads();
    m = fmaxf(fmaxf(red_sh[0], red_sh[1]), fmaxf(red_sh[2], red_sh[3]));
    __syncthreads();
    float s = 0.0f;
    for (int t = tid; t < TT; t += 256) {
        const float e = __expf(logit_sh[t] - m);
        logit_sh[t] = e;
        s += e;
    }
    #pragma unroll
    for (int off = 32; off > 0; off >>= 1) s += __shfl_xor(s, off, 64);
    if (lane == 0) red_sh[wave] = s;
    __syncthreads();
    s = red_sh[0] + red_sh[1] + red_sh[2] + red_sh[3];
    const float inv_s = 1.0f / s;

    float acc = 0.0f;
    for (int t = wave; t < TT; t += 4)
        acc += logit_sh[t] * bf2f(out2[((size_t)b*TT + t)*64 + lane]);
    ctx_sh[wave][lane] = acc;
    __syncthreads();
    if (wave == 0) {
        const float c = (ctx_sh[0][lane] + ctx_sh[1][lane] +
                         ctx_sh[2][lane] + ctx_sh[3][lane]) * inv_s;
        float v = c * fc_w[lane];
        #pragma unroll
        for (int off = 32; off > 0; off >>= 1) v += __shfl_xor(v, off, 64);
        if (lane == 0) out[b] = sigmoidf_(v + fc_b[0]);
    }
}

extern "C" void kernel_launch(void* const* d_in, const int* in_sizes, int n_in,
                              void* d_out, int out_size, void* d_ws, size_t ws_size,
                              hipStream_t stream) {
    (void)in_sizes; (void)n_in; (void)out_size; (void)ws_size;
    const float* x      = (const float*)d_in[0];
    const float* w_ih0  = (const float*)d_in[1];
    const float* w_hh0  = (const float*)d_in[2];
    const float* b_ih0  = (const float*)d_in[3];
    const float* b_hh0  = (const float*)d_in[4];
    const float* w_ih1  = (const float*)d_in[5];
    const float* w_hh1  = (const float*)d_in[6];
    const float* b_ih1  = (const float*)d_in[7];
    const float* b_hh1  = (const float*)d_in[8];
    const float* attn_w = (const float*)d_in[9];
    const float* attn_b = (const float*)d_in[10];
    const float* fc_w   = (const float*)d_in[11];
    const float* fc_b   = (const float*)d_in[12];
    float* out = (float*)d_out;

    unsigned short* h1 = (unsigned short*)d_ws;                        // 67.1 MB bf16
    unsigned short* o2 = (unsigned short*)((char*)d_ws + 134217728);   // 67.1 MB bf16

    gru_l0<<<128, 128, 0, stream>>>(x, w_ih0, w_hh0, b_ih0, b_hh0, h1);
    gru_l1<<<128, 128, 0, stream>>>(h1, w_ih1, w_hh1, b_ih1, b_hh1, o2);
    attn_fc<<<BB, 256, 0, stream>>>(o2, attn_w, attn_b, fc_w, fc_b, out);
}